// Round 2
// baseline (361.554 us; speedup 1.0000x reference)
//
#include <hip/hip_runtime.h>

// Problem constants (fixed by the dataset)
constexpr int S_  = 4096;
constexpr int B_  = 2;
constexpr int C_  = 256;
constexpr int H_  = 8;
constexpr int E_  = 131072;
constexpr int MR  = S_ * B_;   // 8192 rows for all GEMMs
constexpr int NB  = 512;       // persistent grid: 2 blocks/CU x 256 CUs (exact residency)

typedef __attribute__((ext_vector_type(8))) short bf16x8_t;
typedef __attribute__((ext_vector_type(4))) float f32x4_t;

__device__ __forceinline__ unsigned short f2bf(float f) {
    unsigned int u = __float_as_uint(f);
    u += 0x7fffu + ((u >> 16) & 1u);   // round-to-nearest-even
    return (unsigned short)(u >> 16);
}
__device__ __forceinline__ float bflo(unsigned int u) { return __uint_as_float(u << 16); }
__device__ __forceinline__ float bfhi(unsigned int u) { return __uint_as_float(u & 0xffff0000u); }

__device__ __forceinline__ void cast8(const float* __restrict__ src, unsigned short* __restrict__ dst, int i) {
    const float4* s = (const float4*)src + (size_t)i * 2;
    float4 a = s[0], b = s[1];
    uint4 o;
    o.x = (unsigned)f2bf(a.x) | ((unsigned)f2bf(a.y) << 16);
    o.y = (unsigned)f2bf(a.z) | ((unsigned)f2bf(a.w) << 16);
    o.z = (unsigned)f2bf(b.x) | ((unsigned)f2bf(b.y) << 16);
    o.w = (unsigned)f2bf(b.z) | ((unsigned)f2bf(b.w) << 16);
    *((uint4*)dst + i) = o;
}

// Device-wide barrier: monotonic arrival counter, all NB blocks resident.
__device__ __forceinline__ void gbar(int* bar, int target) {
    __syncthreads();
    if (threadIdx.x == 0) {
        __threadfence();                         // release: publish my writes
        atomicAdd(bar, 1);                       // device-scope arrive
        while (atomicAdd(bar, 0) < target)       // device-scope poll
            __builtin_amdgcn_s_sleep(2);
        __threadfence();                         // acquire: invalidate stale caches
    }
    __syncthreads();
}

__global__ __launch_bounds__(256, 2) void fused_kernel(
        const float* __restrict__ x, const int* __restrict__ q_id, const int* __restrict__ k_id,
        const float* __restrict__ Wq, const float* __restrict__ bq,
        const float* __restrict__ Wk, const float* __restrict__ bk,
        const float* __restrict__ Wv, const float* __restrict__ bv,
        const float* __restrict__ Wx, const float* __restrict__ bx,
        unsigned short* __restrict__ xb, unsigned short* __restrict__ qb,
        unsigned short* __restrict__ kvb, unsigned short* __restrict__ attnb,
        unsigned short* __restrict__ Wb,
        int* __restrict__ count, int* bar, int* __restrict__ base,
        int* __restrict__ cursor, int* __restrict__ koff,
        float* __restrict__ out) {
    __shared__ __align__(16) unsigned short As[64][264];   // 33.8 KB; 2 blocks/CU
    const int bid = blockIdx.x, tid = threadIdx.x;
    const int gid = bid * 256 + tid;                       // 0..131071
    const int lane = tid & 63, wave = tid >> 6;
    const int l16 = lane & 15, quad = lane >> 4;

    // ================= P1: cast x + cast W + histogram =================
    cast8(x, xb, gid);
    cast8(x, xb, gid + 131072);
    if (gid < 32768) {
        int z = gid >> 13, i = gid & 8191;
        const float* src = (z == 0) ? Wq : (z == 1) ? Wk : (z == 2) ? Wv : Wx;
        cast8(src, Wb + (size_t)z * (C_ * C_), i);
    }
    atomicAdd(&count[q_id[gid]], 1);
    gbar(bar, NB);

    // ================= P2: scan (block 0) + QKV GEMM (all blocks) =================
    if (bid == 0) {
        const int4* cp = (const int4*)count;
        int4 c0 = cp[tid * 4 + 0], c1 = cp[tid * 4 + 1];
        int4 c2 = cp[tid * 4 + 2], c3 = cp[tid * 4 + 3];
        int tsum = c0.x + c0.y + c0.z + c0.w + c1.x + c1.y + c1.z + c1.w
                 + c2.x + c2.y + c2.z + c2.w + c3.x + c3.y + c3.z + c3.w;
        int incl = tsum;
        const int w = tid >> 6;
#pragma unroll
        for (int off = 1; off < 64; off <<= 1) {
            int y = __shfl_up(incl, off);
            if (lane >= off) incl += y;
        }
        int* wsums = (int*)As;
        if (lane == 63) wsums[w] = incl;
        __syncthreads();
        int ws0 = wsums[0], ws1 = wsums[1], ws2 = wsums[2], ws3 = wsums[3];
        __syncthreads();
        if (tid == 0) base[S_] = ws0 + ws1 + ws2 + ws3;
        int woff = (w > 0 ? ws0 : 0) + (w > 1 ? ws1 : 0) + (w > 2 ? ws2 : 0);
        int run = woff + incl - tsum;
        int idx = tid * 16;
#define EMIT(V) { base[idx] = run; cursor[idx] = run; run += (V); ++idx; }
        EMIT(c0.x) EMIT(c0.y) EMIT(c0.z) EMIT(c0.w)
        EMIT(c1.x) EMIT(c1.y) EMIT(c1.z) EMIT(c1.w)
        EMIT(c2.x) EMIT(c2.y) EMIT(c2.z) EMIT(c2.w)
        EMIT(c3.x) EMIT(c3.y) EMIT(c3.z) EMIT(c3.w)
#undef EMIT
    }
    // QKV GEMM: 1024 units (4 n-blocks x 256 m-groups of 32 rows), 2 units/block
    for (int u = bid; u < 1024; u += NB) {
        const int nb = u & 3, mg = u >> 2;
        const int mbase = mg * 32;
        __syncthreads();
#pragma unroll
        for (int it = 0; it < 4; ++it) {
            int l = it * 256 + tid;
            int r = l >> 5, cc = (l & 31) << 3;
            *(uint4*)&As[r][cc] = *(const uint4*)&xb[(size_t)(mbase + r) * C_ + cc];
        }
        __syncthreads();
        const int colz = (nb << 6) + (wave << 4);
#pragma unroll
        for (int z = 0; z < 3; ++z) {
            const unsigned short* Wrow = Wb + (size_t)z * (C_ * C_) + (size_t)(colz + l16) * C_;
            bf16x8_t breg[8];
#pragma unroll
            for (int ks = 0; ks < 8; ++ks)
                breg[ks] = *(const bf16x8_t*)(Wrow + ks * 32 + quad * 8);
            const float* bias = (z == 0) ? bq : (z == 1) ? bk : bv;
            const float bcol = bias[colz + l16];
#pragma unroll
            for (int mt = 0; mt < 2; ++mt) {
                f32x4_t acc = {0.f, 0.f, 0.f, 0.f};
#pragma unroll
                for (int ks = 0; ks < 8; ++ks) {
                    bf16x8_t a = *(const bf16x8_t*)&As[mt * 16 + l16][ks * 32 + quad * 8];
                    acc = __builtin_amdgcn_mfma_f32_16x16x32_bf16(a, breg[ks], acc, 0, 0, 0);
                }
                const int row0 = mbase + mt * 16 + quad * 4;
                if (z == 0) {
#pragma unroll
                    for (int r = 0; r < 4; ++r)
                        qb[(size_t)(row0 + r) * 256 + colz + l16] = f2bf(acc[r] + bcol);
                } else if (z == 1) {
#pragma unroll
                    for (int r = 0; r < 4; ++r)
                        kvb[(size_t)(row0 + r) * 512 + colz + l16] = f2bf(acc[r] + bcol);
                } else {
#pragma unroll
                    for (int r = 0; r < 4; ++r)
                        kvb[(size_t)(row0 + r) * 512 + 256 + colz + l16] = f2bf(acc[r] + bcol);
                }
            }
        }
    }
    gbar(bar, 2 * NB);

    // ================= P3: scatter edges by q (sorted positions) =================
    {
        int pos = atomicAdd(&cursor[q_id[gid]], 1);
        koff[pos] = k_id[gid] << 10;             // element offset of row-pair in kvb
    }
    gbar(bar, 3 * NB);

    // ================= P4: edge attention (1 wave = 1 seq position) =================
    {
        const int half = lane >> 5, hl = lane & 31;
        const float scale = 0.17677669529663687f;   // 1/sqrt(32)
#pragma unroll
        for (int it = 0; it < 2; ++it) {
            const int s = (bid << 3) + (it << 2) + wave;
            const int e0 = __builtin_amdgcn_readfirstlane(base[s]);
            const int e1 = __builtin_amdgcn_readfirstlane(base[s + 1]);

            const uint4 qq = *((const uint4*)(qb + (size_t)(s * 2 + half) * C_) + hl);
            const float q0 = bflo(qq.x), q1 = bfhi(qq.x), q2 = bflo(qq.y), q3 = bfhi(qq.y);
            const float q4 = bflo(qq.z), q5 = bfhi(qq.z), q6 = bflo(qq.w), q7 = bfhi(qq.w);

            float a0 = 0.f, a1 = 0.f, a2 = 0.f, a3 = 0.f;
            float a4 = 0.f, a5 = 0.f, a6 = 0.f, a7 = 0.f;
            float wsum = 0.f;

            auto edge = [&](const uint4& kk, const uint4& vv) {
                float p = q0 * bflo(kk.x) + q1 * bfhi(kk.x)
                        + q2 * bflo(kk.y) + q3 * bfhi(kk.y)
                        + q4 * bflo(kk.z) + q5 * bfhi(kk.z)
                        + q6 * bflo(kk.w) + q7 * bfhi(kk.w);
                p += __shfl_xor(p, 1);
                p += __shfl_xor(p, 2);
                const float w = __expf(p * scale);
                a0 = fmaf(w, bflo(vv.x), a0); a1 = fmaf(w, bfhi(vv.x), a1);
                a2 = fmaf(w, bflo(vv.y), a2); a3 = fmaf(w, bfhi(vv.y), a3);
                a4 = fmaf(w, bflo(vv.z), a4); a5 = fmaf(w, bfhi(vv.z), a5);
                a6 = fmaf(w, bflo(vv.w), a6); a7 = fmaf(w, bfhi(vv.w), a7);
                wsum += w;
            };
            auto fetch = [&](int my, int t, uint4& kk, uint4& vv) {
                int o = __builtin_amdgcn_readlane(my, t);
                const uint4* p = (const uint4*)(kvb + o + half * 512);
                kk = p[hl]; vv = p[32 + hl];
            };

            for (int b0 = e0; b0 < e1; b0 += 64) {
                const int m = min(64, e1 - b0);
                const int my = koff[b0 + ((lane < m) ? lane : 0)];
                uint4 k0 = {}, v0 = {}, k1 = {}, v1 = {};
                uint4 k2 = {}, v2 = {}, k3 = {}, v3 = {};
                if (m > 0) fetch(my, 0, k0, v0);
                if (m > 1) fetch(my, 1, k1, v1);
                if (m > 2) fetch(my, 2, k2, v2);
                if (m > 3) fetch(my, 3, k3, v3);
                int t = 0;
                for (; t + 7 < m; t += 4) {
                    edge(k0, v0); fetch(my, t + 4, k0, v0);
                    edge(k1, v1); fetch(my, t + 5, k1, v1);
                    edge(k2, v2); fetch(my, t + 6, k2, v2);
                    edge(k3, v3); fetch(my, t + 7, k3, v3);
                }
                const int rem = m - t;   // 0..7
                if (rem > 0) { edge(k0, v0); if (rem > 4) fetch(my, t + 4, k0, v0); }
                if (rem > 1) { edge(k1, v1); if (rem > 5) fetch(my, t + 5, k1, v1); }
                if (rem > 2) { edge(k2, v2); if (rem > 6) fetch(my, t + 6, k2, v2); }
                if (rem > 3) edge(k3, v3);
                if (rem > 4) edge(k0, v0);
                if (rem > 5) edge(k1, v1);
                if (rem > 6) edge(k2, v2);
            }

            const float inv = 1.0f / wsum;
            uint4 o;
            o.x = (unsigned)f2bf(a0 * inv) | ((unsigned)f2bf(a1 * inv) << 16);
            o.y = (unsigned)f2bf(a2 * inv) | ((unsigned)f2bf(a3 * inv) << 16);
            o.z = (unsigned)f2bf(a4 * inv) | ((unsigned)f2bf(a5 * inv) << 16);
            o.w = (unsigned)f2bf(a6 * inv) | ((unsigned)f2bf(a7 * inv) << 16);
            *((uint4*)(attnb + (size_t)(s * 2 + half) * C_) + hl) = o;
        }
    }
    gbar(bar, 4 * NB);

    // ================= P5: output projection (512 units, 1/block) =================
    {
        const int nbp = bid & 3, mgp = bid >> 2;
        const int mbase = mgp * 64;
#pragma unroll
        for (int it = 0; it < 8; ++it) {
            int l = it * 256 + tid;
            int r = l >> 5, cc = (l & 31) << 3;
            *(uint4*)&As[r][cc] = *(const uint4*)&attnb[(size_t)(mbase + r) * C_ + cc];
        }
        __syncthreads();
        const int colz = (nbp << 6) + (wave << 4);
        const unsigned short* Wrow = Wb + (size_t)3 * (C_ * C_) + (size_t)(colz + l16) * C_;
        bf16x8_t breg[8];
#pragma unroll
        for (int ks = 0; ks < 8; ++ks)
            breg[ks] = *(const bf16x8_t*)(Wrow + ks * 32 + quad * 8);
        const float bcol = bx[colz + l16];
#pragma unroll
        for (int mt = 0; mt < 4; ++mt) {
            f32x4_t acc = {0.f, 0.f, 0.f, 0.f};
#pragma unroll
            for (int ks = 0; ks < 8; ++ks) {
                bf16x8_t a = *(const bf16x8_t*)&As[mt * 16 + l16][ks * 32 + quad * 8];
                acc = __builtin_amdgcn_mfma_f32_16x16x32_bf16(a, breg[ks], acc, 0, 0, 0);
            }
            const int row0 = mbase + mt * 16 + quad * 4;
#pragma unroll
            for (int r = 0; r < 4; ++r)
                out[(size_t)(row0 + r) * C_ + colz + l16] = acc[r] + bcol;
        }
    }
}

// ---------------- launch ----------------

extern "C" void kernel_launch(void* const* d_in, const int* in_sizes, int n_in,
                              void* d_out, int out_size, void* d_ws, size_t ws_size,
                              hipStream_t stream) {
    const float* x  = (const float*)d_in[0];
    const int* q_id = (const int*)d_in[1];
    const int* k_id = (const int*)d_in[2];
    const float* Wq = (const float*)d_in[3];
    const float* bq = (const float*)d_in[4];
    const float* Wk = (const float*)d_in[5];
    const float* bk = (const float*)d_in[6];
    const float* Wv = (const float*)d_in[7];
    const float* bv = (const float*)d_in[8];
    const float* Wx = (const float*)d_in[9];
    const float* bx = (const float*)d_in[10];
    float* out = (float*)d_out;

    char* ws = (char*)d_ws;
    unsigned short* xb    = (unsigned short*)ws;   ws += (size_t)MR * C_ * 2;
    unsigned short* qb    = (unsigned short*)ws;   ws += (size_t)MR * C_ * 2;
    unsigned short* kvb   = (unsigned short*)ws;   ws += (size_t)MR * 512 * 2;
    unsigned short* attnb = (unsigned short*)ws;   ws += (size_t)MR * C_ * 2;
    unsigned short* Wb    = (unsigned short*)ws;   ws += (size_t)4 * C_ * C_ * 2;
    int* count = (int*)ws;                         ws += S_ * 4;
    int* bar   = (int*)ws;                         ws += 8 * 4;
    int* base  = (int*)ws;                         ws += (S_ + 1) * 4;
    int* cursor = (int*)ws;                        ws += S_ * 4;
    int* koff_sorted = (int*)ws;

    hipMemsetAsync(count, 0, (S_ + 8) * sizeof(int), stream);   // count + bar
    fused_kernel<<<NB, 256, 0, stream>>>(x, q_id, k_id, Wq, bq, Wk, bk, Wv, bv, Wx, bx,
                                         xb, qb, kvb, attnb, Wb,
                                         count, bar, base, cursor, koff_sorted, out);
}

// Round 3
// 176.782 us; speedup vs baseline: 2.0452x; 2.0452x over previous
//
#include <hip/hip_runtime.h>

// Problem constants (fixed by the dataset)
constexpr int S_  = 4096;
constexpr int B_  = 2;
constexpr int C_  = 256;
constexpr int H_  = 8;
constexpr int E_  = 131072;
constexpr int MR  = S_ * B_;   // 8192 rows for all GEMMs
constexpr int NB  = 512;       // persistent grid: 2 blocks/CU x 256 CUs (exact residency)

typedef __attribute__((ext_vector_type(8))) short bf16x8_t;
typedef __attribute__((ext_vector_type(4))) float f32x4_t;

__device__ __forceinline__ unsigned short f2bf(float f) {
    unsigned int u = __float_as_uint(f);
    u += 0x7fffu + ((u >> 16) & 1u);   // round-to-nearest-even
    return (unsigned short)(u >> 16);
}
__device__ __forceinline__ float bflo(unsigned int u) { return __uint_as_float(u << 16); }
__device__ __forceinline__ float bfhi(unsigned int u) { return __uint_as_float(u & 0xffff0000u); }

__device__ __forceinline__ void cast8(const float* __restrict__ src, unsigned short* __restrict__ dst, int i) {
    const float4* s = (const float4*)src + (size_t)i * 2;
    float4 a = s[0], b = s[1];
    uint4 o;
    o.x = (unsigned)f2bf(a.x) | ((unsigned)f2bf(a.y) << 16);
    o.y = (unsigned)f2bf(a.z) | ((unsigned)f2bf(a.w) << 16);
    o.z = (unsigned)f2bf(b.x) | ((unsigned)f2bf(b.y) << 16);
    o.w = (unsigned)f2bf(b.z) | ((unsigned)f2bf(b.w) << 16);
    *((uint4*)dst + i) = o;
}

// ---- barrier state layout (ints, inside zeroed ws region right after count) ----
// [0] reg_cnt  [1] ready  [16+x*16] xcd_cnt  [144+(ph*8+x)*16] larr
// [656+ph*16] gcnt  [720+x*16] go          total 848 ints
#define BST_REG   0
#define BST_RDY   1
#define BST_XCNT(x)    (16 + (x) * 16)
#define BST_LARR(p, x) (144 + ((p) * 8 + (x)) * 16)
#define BST_GCNT(p)    (656 + (p) * 16)
#define BST_GO(x)      (720 + (x) * 16)
constexpr int BST_INTS = 848;

__device__ __forceinline__ int get_xcc_id() {
    int x;
    asm volatile("s_getreg_b32 %0, hwreg(HW_REG_XCC_ID)" : "=s"(x));
    return x & 7;
}

// Two-level device barrier: 1 relaxed arrive per block; last arriver per XCD
// does the single wbL2 (release) / invL2 (acquire) for its chiplet.
__device__ __forceinline__ void gbar2(int* bst, int xcd, int xcnt, int ngrp, int ph) {
    __syncthreads();   // drains all block stores to L2 (compiler emits vmcnt(0) before s_barrier)
    if (threadIdx.x == 0) {
        int ret = __hip_atomic_fetch_add(&bst[BST_LARR(ph, xcd)], 1,
                                         __ATOMIC_RELAXED, __HIP_MEMORY_SCOPE_AGENT);
        if (ret == xcnt - 1) {
            // I'm the flusher for this XCD: all local stores are in this L2.
            __builtin_amdgcn_fence(__ATOMIC_RELEASE, "agent");     // one buffer_wbl2
            __hip_atomic_fetch_add(&bst[BST_GCNT(ph)], 1,
                                   __ATOMIC_RELAXED, __HIP_MEMORY_SCOPE_AGENT);
            while (__hip_atomic_load(&bst[BST_GCNT(ph)], __ATOMIC_RELAXED,
                                     __HIP_MEMORY_SCOPE_AGENT) < ngrp)
                __builtin_amdgcn_s_sleep(4);
            __builtin_amdgcn_fence(__ATOMIC_ACQUIRE, "agent");     // one buffer_inv
            __hip_atomic_store(&bst[BST_GO(xcd)], ph + 1,
                               __ATOMIC_RELEASE, __HIP_MEMORY_SCOPE_AGENT);
        } else {
            while (__hip_atomic_load(&bst[BST_GO(xcd)], __ATOMIC_RELAXED,
                                     __HIP_MEMORY_SCOPE_AGENT) < ph + 1)
                __builtin_amdgcn_s_sleep(2);
            __builtin_amdgcn_sched_barrier(0);
        }
    }
    __syncthreads();
}

__global__ __launch_bounds__(256, 2) void fused_kernel(
        const float* __restrict__ x, const int* __restrict__ q_id, const int* __restrict__ k_id,
        const float* __restrict__ Wq, const float* __restrict__ bq,
        const float* __restrict__ Wk, const float* __restrict__ bk,
        const float* __restrict__ Wv, const float* __restrict__ bv,
        const float* __restrict__ Wx, const float* __restrict__ bx,
        unsigned short* __restrict__ xb, unsigned short* __restrict__ qb,
        unsigned short* __restrict__ kvb, unsigned short* __restrict__ attnb,
        unsigned short* __restrict__ Wb,
        int* __restrict__ count, int* bst, int* __restrict__ base,
        int* __restrict__ cursor, int* __restrict__ koff,
        float* __restrict__ out) {
    __shared__ __align__(16) unsigned short As[64][264];   // 33.8 KB; 2 blocks/CU
    const int bid = blockIdx.x, tid = threadIdx.x;
    const int gid = bid * 256 + tid;                       // 0..131071
    const int lane = tid & 63, wave = tid >> 6;
    const int l16 = lane & 15, quad = lane >> 4;

    // ================= P1: cast x + cast W + histogram =================
    cast8(x, xb, gid);
    cast8(x, xb, gid + 131072);
    if (gid < 32768) {
        int z = gid >> 13, i = gid & 8191;
        const float* src = (z == 0) ? Wq : (z == 1) ? Wk : (z == 2) ? Wv : Wx;
        cast8(src, Wb + (size_t)z * (C_ * C_), i);
    }
    atomicAdd(&count[q_id[gid]], 1);

    // ---- one-time XCD registration (fence-free rendezvous; only atomics cross it) ----
    __syncthreads();
    int xcd = 0, xcnt = 0, ngrp = 0;
    if (tid == 0) {
        xcd = get_xcc_id();
        __hip_atomic_fetch_add(&bst[BST_XCNT(xcd)], 1, __ATOMIC_RELAXED, __HIP_MEMORY_SCOPE_AGENT);
        int ord = __hip_atomic_fetch_add(&bst[BST_REG], 1, __ATOMIC_RELEASE, __HIP_MEMORY_SCOPE_AGENT);
        if (ord == NB - 1)
            __hip_atomic_store(&bst[BST_RDY], 1, __ATOMIC_RELEASE, __HIP_MEMORY_SCOPE_AGENT);
        while (!__hip_atomic_load(&bst[BST_RDY], __ATOMIC_RELAXED, __HIP_MEMORY_SCOPE_AGENT))
            __builtin_amdgcn_s_sleep(2);
        __builtin_amdgcn_sched_barrier(0);
#pragma unroll
        for (int i = 0; i < 8; ++i) {
            int c = __hip_atomic_load(&bst[BST_XCNT(i)], __ATOMIC_RELAXED, __HIP_MEMORY_SCOPE_AGENT);
            ngrp += (c > 0) ? 1 : 0;
            if (i == xcd) xcnt = c;
        }
    }
    gbar2(bst, xcd, xcnt, ngrp, 0);

    // ================= P2: scan (block 0) + QKV GEMM (all blocks) =================
    if (bid == 0) {
        const int4* cp = (const int4*)count;
        int4 c0 = cp[tid * 4 + 0], c1 = cp[tid * 4 + 1];
        int4 c2 = cp[tid * 4 + 2], c3 = cp[tid * 4 + 3];
        int tsum = c0.x + c0.y + c0.z + c0.w + c1.x + c1.y + c1.z + c1.w
                 + c2.x + c2.y + c2.z + c2.w + c3.x + c3.y + c3.z + c3.w;
        int incl = tsum;
        const int w = tid >> 6;
#pragma unroll
        for (int off = 1; off < 64; off <<= 1) {
            int y = __shfl_up(incl, off);
            if (lane >= off) incl += y;
        }
        int* wsums = (int*)As;
        if (lane == 63) wsums[w] = incl;
        __syncthreads();
        int ws0 = wsums[0], ws1 = wsums[1], ws2 = wsums[2], ws3 = wsums[3];
        __syncthreads();
        if (tid == 0) base[S_] = ws0 + ws1 + ws2 + ws3;
        int woff = (w > 0 ? ws0 : 0) + (w > 1 ? ws1 : 0) + (w > 2 ? ws2 : 0);
        int run = woff + incl - tsum;
        int idx = tid * 16;
#define EMIT(V) { base[idx] = run; cursor[idx] = run; run += (V); ++idx; }
        EMIT(c0.x) EMIT(c0.y) EMIT(c0.z) EMIT(c0.w)
        EMIT(c1.x) EMIT(c1.y) EMIT(c1.z) EMIT(c1.w)
        EMIT(c2.x) EMIT(c2.y) EMIT(c2.z) EMIT(c2.w)
        EMIT(c3.x) EMIT(c3.y) EMIT(c3.z) EMIT(c3.w)
#undef EMIT
    }
    // QKV GEMM: 1024 units (4 n-blocks x 256 m-groups of 32 rows), 2 units/block
    for (int u = bid; u < 1024; u += NB) {
        const int nb = u & 3, mg = u >> 2;
        const int mbase = mg * 32;
        __syncthreads();
#pragma unroll
        for (int it = 0; it < 4; ++it) {
            int l = it * 256 + tid;
            int r = l >> 5, cc = (l & 31) << 3;
            *(uint4*)&As[r][cc] = *(const uint4*)&xb[(size_t)(mbase + r) * C_ + cc];
        }
        __syncthreads();
        const int colz = (nb << 6) + (wave << 4);
#pragma unroll
        for (int z = 0; z < 3; ++z) {
            const unsigned short* Wrow = Wb + (size_t)z * (C_ * C_) + (size_t)(colz + l16) * C_;
            bf16x8_t breg[8];
#pragma unroll
            for (int ks = 0; ks < 8; ++ks)
                breg[ks] = *(const bf16x8_t*)(Wrow + ks * 32 + quad * 8);
            const float* bias = (z == 0) ? bq : (z == 1) ? bk : bv;
            const float bcol = bias[colz + l16];
#pragma unroll
            for (int mt = 0; mt < 2; ++mt) {
                f32x4_t acc = {0.f, 0.f, 0.f, 0.f};
#pragma unroll
                for (int ks = 0; ks < 8; ++ks) {
                    bf16x8_t a = *(const bf16x8_t*)&As[mt * 16 + l16][ks * 32 + quad * 8];
                    acc = __builtin_amdgcn_mfma_f32_16x16x32_bf16(a, breg[ks], acc, 0, 0, 0);
                }
                const int row0 = mbase + mt * 16 + quad * 4;
                if (z == 0) {
#pragma unroll
                    for (int r = 0; r < 4; ++r)
                        qb[(size_t)(row0 + r) * 256 + colz + l16] = f2bf(acc[r] + bcol);
                } else if (z == 1) {
#pragma unroll
                    for (int r = 0; r < 4; ++r)
                        kvb[(size_t)(row0 + r) * 512 + colz + l16] = f2bf(acc[r] + bcol);
                } else {
#pragma unroll
                    for (int r = 0; r < 4; ++r)
                        kvb[(size_t)(row0 + r) * 512 + 256 + colz + l16] = f2bf(acc[r] + bcol);
                }
            }
        }
    }
    gbar2(bst, xcd, xcnt, ngrp, 1);

    // ================= P3: scatter edges by q (sorted positions) =================
    {
        int pos = atomicAdd(&cursor[q_id[gid]], 1);
        koff[pos] = k_id[gid] << 10;             // element offset of row-pair in kvb
    }
    gbar2(bst, xcd, xcnt, ngrp, 2);

    // ================= P4: edge attention (1 wave = 1 seq position) =================
    {
        const int half = lane >> 5, hl = lane & 31;
        const float scale = 0.17677669529663687f;   // 1/sqrt(32)
#pragma unroll
        for (int it = 0; it < 2; ++it) {
            const int s = (bid << 3) + (it << 2) + wave;
            const int e0 = __builtin_amdgcn_readfirstlane(base[s]);
            const int e1 = __builtin_amdgcn_readfirstlane(base[s + 1]);

            const uint4 qq = *((const uint4*)(qb + (size_t)(s * 2 + half) * C_) + hl);
            const float q0 = bflo(qq.x), q1 = bfhi(qq.x), q2 = bflo(qq.y), q3 = bfhi(qq.y);
            const float q4 = bflo(qq.z), q5 = bfhi(qq.z), q6 = bflo(qq.w), q7 = bfhi(qq.w);

            float a0 = 0.f, a1 = 0.f, a2 = 0.f, a3 = 0.f;
            float a4 = 0.f, a5 = 0.f, a6 = 0.f, a7 = 0.f;
            float wsum = 0.f;

            auto edge = [&](const uint4& kk, const uint4& vv) {
                float p = q0 * bflo(kk.x) + q1 * bfhi(kk.x)
                        + q2 * bflo(kk.y) + q3 * bfhi(kk.y)
                        + q4 * bflo(kk.z) + q5 * bfhi(kk.z)
                        + q6 * bflo(kk.w) + q7 * bfhi(kk.w);
                p += __shfl_xor(p, 1);
                p += __shfl_xor(p, 2);
                const float w = __expf(p * scale);
                a0 = fmaf(w, bflo(vv.x), a0); a1 = fmaf(w, bfhi(vv.x), a1);
                a2 = fmaf(w, bflo(vv.y), a2); a3 = fmaf(w, bfhi(vv.y), a3);
                a4 = fmaf(w, bflo(vv.z), a4); a5 = fmaf(w, bfhi(vv.z), a5);
                a6 = fmaf(w, bflo(vv.w), a6); a7 = fmaf(w, bfhi(vv.w), a7);
                wsum += w;
            };
            auto fetch = [&](int my, int t, uint4& kk, uint4& vv) {
                int o = __builtin_amdgcn_readlane(my, t);
                const uint4* p = (const uint4*)(kvb + o + half * 512);
                kk = p[hl]; vv = p[32 + hl];
            };

            for (int b0 = e0; b0 < e1; b0 += 64) {
                const int m = min(64, e1 - b0);
                const int my = koff[b0 + ((lane < m) ? lane : 0)];
                uint4 k0 = {}, v0 = {}, k1 = {}, v1 = {};
                uint4 k2 = {}, v2 = {}, k3 = {}, v3 = {};
                if (m > 0) fetch(my, 0, k0, v0);
                if (m > 1) fetch(my, 1, k1, v1);
                if (m > 2) fetch(my, 2, k2, v2);
                if (m > 3) fetch(my, 3, k3, v3);
                int t = 0;
                for (; t + 7 < m; t += 4) {
                    edge(k0, v0); fetch(my, t + 4, k0, v0);
                    edge(k1, v1); fetch(my, t + 5, k1, v1);
                    edge(k2, v2); fetch(my, t + 6, k2, v2);
                    edge(k3, v3); fetch(my, t + 7, k3, v3);
                }
                const int rem = m - t;   // 0..7
                if (rem > 0) { edge(k0, v0); if (rem > 4) fetch(my, t + 4, k0, v0); }
                if (rem > 1) { edge(k1, v1); if (rem > 5) fetch(my, t + 5, k1, v1); }
                if (rem > 2) { edge(k2, v2); if (rem > 6) fetch(my, t + 6, k2, v2); }
                if (rem > 3) edge(k3, v3);
                if (rem > 4) edge(k0, v0);
                if (rem > 5) edge(k1, v1);
                if (rem > 6) edge(k2, v2);
            }

            const float inv = 1.0f / wsum;
            uint4 o;
            o.x = (unsigned)f2bf(a0 * inv) | ((unsigned)f2bf(a1 * inv) << 16);
            o.y = (unsigned)f2bf(a2 * inv) | ((unsigned)f2bf(a3 * inv) << 16);
            o.z = (unsigned)f2bf(a4 * inv) | ((unsigned)f2bf(a5 * inv) << 16);
            o.w = (unsigned)f2bf(a6 * inv) | ((unsigned)f2bf(a7 * inv) << 16);
            *((uint4*)(attnb + (size_t)(s * 2 + half) * C_) + hl) = o;
        }
    }
    gbar2(bst, xcd, xcnt, ngrp, 3);

    // ================= P5: output projection (512 units, 1/block) =================
    {
        const int nbp = bid & 3, mgp = bid >> 2;
        const int mbase = mgp * 64;
#pragma unroll
        for (int it = 0; it < 8; ++it) {
            int l = it * 256 + tid;
            int r = l >> 5, cc = (l & 31) << 3;
            *(uint4*)&As[r][cc] = *(const uint4*)&attnb[(size_t)(mbase + r) * C_ + cc];
        }
        __syncthreads();
        const int colz = (nbp << 6) + (wave << 4);
        const unsigned short* Wrow = Wb + (size_t)3 * (C_ * C_) + (size_t)(colz + l16) * C_;
        bf16x8_t breg[8];
#pragma unroll
        for (int ks = 0; ks < 8; ++ks)
            breg[ks] = *(const bf16x8_t*)(Wrow + ks * 32 + quad * 8);
        const float bcol = bx[colz + l16];
#pragma unroll
        for (int mt = 0; mt < 4; ++mt) {
            f32x4_t acc = {0.f, 0.f, 0.f, 0.f};
#pragma unroll
            for (int ks = 0; ks < 8; ++ks) {
                bf16x8_t a = *(const bf16x8_t*)&As[mt * 16 + l16][ks * 32 + quad * 8];
                acc = __builtin_amdgcn_mfma_f32_16x16x32_bf16(a, breg[ks], acc, 0, 0, 0);
            }
            const int row0 = mbase + mt * 16 + quad * 4;
#pragma unroll
            for (int r = 0; r < 4; ++r)
                out[(size_t)(row0 + r) * C_ + colz + l16] = acc[r] + bcol;
        }
    }
}

// ---------------- launch ----------------

extern "C" void kernel_launch(void* const* d_in, const int* in_sizes, int n_in,
                              void* d_out, int out_size, void* d_ws, size_t ws_size,
                              hipStream_t stream) {
    const float* x  = (const float*)d_in[0];
    const int* q_id = (const int*)d_in[1];
    const int* k_id = (const int*)d_in[2];
    const float* Wq = (const float*)d_in[3];
    const float* bq = (const float*)d_in[4];
    const float* Wk = (const float*)d_in[5];
    const float* bk = (const float*)d_in[6];
    const float* Wv = (const float*)d_in[7];
    const float* bv = (const float*)d_in[8];
    const float* Wx = (const float*)d_in[9];
    const float* bx = (const float*)d_in[10];
    float* out = (float*)d_out;

    char* ws = (char*)d_ws;
    unsigned short* xb    = (unsigned short*)ws;   ws += (size_t)MR * C_ * 2;
    unsigned short* qb    = (unsigned short*)ws;   ws += (size_t)MR * C_ * 2;
    unsigned short* kvb   = (unsigned short*)ws;   ws += (size_t)MR * 512 * 2;
    unsigned short* attnb = (unsigned short*)ws;   ws += (size_t)MR * C_ * 2;
    unsigned short* Wb    = (unsigned short*)ws;   ws += (size_t)4 * C_ * C_ * 2;
    int* count = (int*)ws;                         ws += S_ * 4;
    int* bst   = (int*)ws;                         ws += BST_INTS * 4;
    int* base  = (int*)ws;                         ws += (S_ + 1) * 4;
    int* cursor = (int*)ws;                        ws += S_ * 4;
    int* koff_sorted = (int*)ws;

    hipMemsetAsync(count, 0, (S_ + BST_INTS) * sizeof(int), stream);   // count + barrier state
    fused_kernel<<<NB, 256, 0, stream>>>(x, q_id, k_id, Wq, bq, Wk, bk, Wv, bv, Wx, bx,
                                         xb, qb, kvb, attnb, Wb,
                                         count, bst, base, cursor, koff_sorted, out);
}

// Round 4
// 162.357 us; speedup vs baseline: 2.2269x; 1.0889x over previous
//
#include <hip/hip_runtime.h>

// Problem constants (fixed by the dataset)
constexpr int S_  = 4096;
constexpr int B_  = 2;
constexpr int C_  = 256;
constexpr int H_  = 8;
constexpr int E_  = 131072;
constexpr int MR  = S_ * B_;   // 8192 rows for all GEMMs
constexpr int NB  = 512;       // kernel A grid: 2 blocks/CU x 256 CUs (exact residency)

typedef __attribute__((ext_vector_type(8))) short bf16x8_t;
typedef __attribute__((ext_vector_type(4))) float f32x4_t;

__device__ __forceinline__ unsigned short f2bf(float f) {
    unsigned int u = __float_as_uint(f);
    u += 0x7fffu + ((u >> 16) & 1u);   // round-to-nearest-even
    return (unsigned short)(u >> 16);
}
__device__ __forceinline__ float bflo(unsigned int u) { return __uint_as_float(u << 16); }
__device__ __forceinline__ float bfhi(unsigned int u) { return __uint_as_float(u & 0xffff0000u); }

__device__ __forceinline__ void cast8(const float* __restrict__ src, unsigned short* __restrict__ dst, int i) {
    const float4* s = (const float4*)src + (size_t)i * 2;
    float4 a = s[0], b = s[1];
    uint4 o;
    o.x = (unsigned)f2bf(a.x) | ((unsigned)f2bf(a.y) << 16);
    o.y = (unsigned)f2bf(a.z) | ((unsigned)f2bf(a.w) << 16);
    o.z = (unsigned)f2bf(b.x) | ((unsigned)f2bf(b.y) << 16);
    o.w = (unsigned)f2bf(b.z) | ((unsigned)f2bf(b.w) << 16);
    *((uint4*)dst + i) = o;
}

// ---- barrier state layout (ints, zeroed) ----
#define BST_REG   0
#define BST_RDY   1
#define BST_XCNT(x)    (16 + (x) * 16)
#define BST_LARR(p, x) (144 + ((p) * 8 + (x)) * 16)
#define BST_GCNT(p)    (656 + (p) * 16)
#define BST_GO(x)      (720 + (x) * 16)
constexpr int BST_INTS = 848;

__device__ __forceinline__ int get_xcc_id() {
    int x;
    asm volatile("s_getreg_b32 %0, hwreg(HW_REG_XCC_ID)" : "=s"(x));
    return x & 7;
}

// Two-level device barrier: relaxed arrive per block; last arriver per XCD does
// the single wbL2 (release) / invL2 (acquire) for its chiplet.
__device__ __forceinline__ void gbar2(int* bst, int xcd, int xcnt, int ngrp, int ph) {
    __syncthreads();
    if (threadIdx.x == 0) {
        int ret = __hip_atomic_fetch_add(&bst[BST_LARR(ph, xcd)], 1,
                                         __ATOMIC_RELAXED, __HIP_MEMORY_SCOPE_AGENT);
        if (ret == xcnt - 1) {
            __builtin_amdgcn_fence(__ATOMIC_RELEASE, "agent");     // one buffer_wbl2
            __hip_atomic_fetch_add(&bst[BST_GCNT(ph)], 1,
                                   __ATOMIC_RELAXED, __HIP_MEMORY_SCOPE_AGENT);
            while (__hip_atomic_load(&bst[BST_GCNT(ph)], __ATOMIC_RELAXED,
                                     __HIP_MEMORY_SCOPE_AGENT) < ngrp)
                __builtin_amdgcn_s_sleep(4);
            __builtin_amdgcn_fence(__ATOMIC_ACQUIRE, "agent");     // one buffer_inv
            __hip_atomic_store(&bst[BST_GO(xcd)], ph + 1,
                               __ATOMIC_RELEASE, __HIP_MEMORY_SCOPE_AGENT);
        } else {
            while (__hip_atomic_load(&bst[BST_GO(xcd)], __ATOMIC_RELAXED,
                                     __HIP_MEMORY_SCOPE_AGENT) < ph + 1)
                __builtin_amdgcn_s_sleep(2);
            __builtin_amdgcn_sched_barrier(0);
        }
    }
    __syncthreads();
}

// ---------------- Kernel A: casts+hist -> bar -> scan || QKV GEMM -> bar -> scatter ----------------
// count/base/cursor are 2S entries: bucket A (k<2048) at [0,S), bucket B at [S,2S).

__global__ __launch_bounds__(256, 2) void fusedA(
        const float* __restrict__ x, const int* __restrict__ q_id, const int* __restrict__ k_id,
        const float* __restrict__ Wq, const float* __restrict__ bq,
        const float* __restrict__ Wk, const float* __restrict__ bk,
        const float* __restrict__ Wv, const float* __restrict__ bv,
        const float* __restrict__ Wx,
        unsigned short* __restrict__ xb, unsigned short* __restrict__ qb,
        unsigned short* __restrict__ kvb, unsigned short* __restrict__ Wb,
        int* __restrict__ count, int* bst, int* __restrict__ base,
        int* __restrict__ cursor, int* __restrict__ koff) {
    __shared__ __align__(16) unsigned short As[32][264];
    const int bid = blockIdx.x, tid = threadIdx.x;
    const int gid = bid * 256 + tid;                       // 0..131071
    const int lane = tid & 63, wave = tid >> 6;
    const int l16 = lane & 15, quad = lane >> 4;

    // early XCD registration (overlaps launch ramp with P1 work)
    int xcd = 0;
    if (tid == 0) {
        xcd = get_xcc_id();
        __hip_atomic_fetch_add(&bst[BST_XCNT(xcd)], 1, __ATOMIC_RELAXED, __HIP_MEMORY_SCOPE_AGENT);
        int ord = __hip_atomic_fetch_add(&bst[BST_REG], 1, __ATOMIC_RELEASE, __HIP_MEMORY_SCOPE_AGENT);
        if (ord == NB - 1)
            __hip_atomic_store(&bst[BST_RDY], 1, __ATOMIC_RELEASE, __HIP_MEMORY_SCOPE_AGENT);
    }

    // ================= P1: cast x + cast W + bucketed histogram =================
    cast8(x, xb, gid);
    cast8(x, xb, gid + 131072);
    if (gid < 32768) {
        int z = gid >> 13, i = gid & 8191;
        const float* src = (z == 0) ? Wq : (z == 1) ? Wk : (z == 2) ? Wv : Wx;
        cast8(src, Wb + (size_t)z * (C_ * C_), i);
    }
    {
        int q = q_id[gid], k = k_id[gid];
        atomicAdd(&count[q + ((k >> 11) << 12)], 1);   // bucket = k>=2048
    }

    __syncthreads();
    int xcnt = 0, ngrp = 0;
    if (tid == 0) {
        while (!__hip_atomic_load(&bst[BST_RDY], __ATOMIC_RELAXED, __HIP_MEMORY_SCOPE_AGENT))
            __builtin_amdgcn_s_sleep(2);
        __builtin_amdgcn_sched_barrier(0);
#pragma unroll
        for (int i = 0; i < 8; ++i) {
            int c = __hip_atomic_load(&bst[BST_XCNT(i)], __ATOMIC_RELAXED, __HIP_MEMORY_SCOPE_AGENT);
            ngrp += (c > 0) ? 1 : 0;
            if (i == xcd) xcnt = c;
        }
    }
    gbar2(bst, xcd, xcnt, ngrp, 0);

    // ================= P2: scan (block 0) + QKV GEMM (all blocks) =================
    if (bid == 0) {
        const int4* cp = (const int4*)count;
        int4 c[8];
#pragma unroll
        for (int j = 0; j < 8; ++j) c[j] = cp[tid * 8 + j];
        int tsum = 0;
#pragma unroll
        for (int j = 0; j < 8; ++j) tsum += c[j].x + c[j].y + c[j].z + c[j].w;
        int incl = tsum;
        const int w = tid >> 6;
#pragma unroll
        for (int off = 1; off < 64; off <<= 1) {
            int y = __shfl_up(incl, off);
            if (lane >= off) incl += y;
        }
        int* wsums = (int*)As;
        if (lane == 63) wsums[w] = incl;
        __syncthreads();
        int ws0 = wsums[0], ws1 = wsums[1], ws2 = wsums[2], ws3 = wsums[3];
        __syncthreads();
        if (tid == 0) base[2 * S_] = E_;
        int woff = (w > 0 ? ws0 : 0) + (w > 1 ? ws1 : 0) + (w > 2 ? ws2 : 0);
        int run = woff + incl - tsum;
        int idx = tid * 32;
#define EMIT(V) { base[idx] = run; cursor[idx] = run; run += (V); ++idx; }
#pragma unroll
        for (int j = 0; j < 8; ++j) {
            EMIT(c[j].x) EMIT(c[j].y) EMIT(c[j].z) EMIT(c[j].w)
        }
#undef EMIT
    }
    // QKV GEMM: 1024 units (4 n-blocks x 256 m-groups of 32 rows), 2 units/block
    for (int u = bid; u < 1024; u += NB) {
        const int nb = u & 3, mg = u >> 2;
        const int mbase = mg * 32;
        __syncthreads();
#pragma unroll
        for (int it = 0; it < 4; ++it) {
            int l = it * 256 + tid;
            int r = l >> 5, cc = (l & 31) << 3;
            *(uint4*)&As[r][cc] = *(const uint4*)&xb[(size_t)(mbase + r) * C_ + cc];
        }
        __syncthreads();
        const int colz = (nb << 6) + (wave << 4);
#pragma unroll
        for (int z = 0; z < 3; ++z) {
            const unsigned short* Wrow = Wb + (size_t)z * (C_ * C_) + (size_t)(colz + l16) * C_;
            bf16x8_t breg[8];
#pragma unroll
            for (int ks = 0; ks < 8; ++ks)
                breg[ks] = *(const bf16x8_t*)(Wrow + ks * 32 + quad * 8);
            const float* bias = (z == 0) ? bq : (z == 1) ? bk : bv;
            const float bcol = bias[colz + l16];
#pragma unroll
            for (int mt = 0; mt < 2; ++mt) {
                f32x4_t acc = {0.f, 0.f, 0.f, 0.f};
#pragma unroll
                for (int ks = 0; ks < 8; ++ks) {
                    bf16x8_t a = *(const bf16x8_t*)&As[mt * 16 + l16][ks * 32 + quad * 8];
                    acc = __builtin_amdgcn_mfma_f32_16x16x32_bf16(a, breg[ks], acc, 0, 0, 0);
                }
                const int row0 = mbase + mt * 16 + quad * 4;
                if (z == 0) {
#pragma unroll
                    for (int r = 0; r < 4; ++r)
                        qb[(size_t)(row0 + r) * 256 + colz + l16] = f2bf(acc[r] + bcol);
                } else if (z == 1) {
#pragma unroll
                    for (int r = 0; r < 4; ++r)
                        kvb[(size_t)(row0 + r) * 512 + colz + l16] = f2bf(acc[r] + bcol);
                } else {
#pragma unroll
                    for (int r = 0; r < 4; ++r)
                        kvb[(size_t)(row0 + r) * 512 + 256 + colz + l16] = f2bf(acc[r] + bcol);
                }
            }
        }
    }
    gbar2(bst, xcd, xcnt, ngrp, 1);

    // ================= P3: scatter edges by (q, k-bucket) =================
    {
        int q = q_id[gid], k = k_id[gid];
        int pos = atomicAdd(&cursor[q + ((k >> 11) << 12)], 1);
        koff[pos] = k << 10;                 // element offset of row-pair in kvb
    }
}

// ---------------- Kernel B: edge attention, k-bucketed two-pass gather ----------------
// 2048 blocks; block covers 2 seq positions, 2 waves (parts) each; high occupancy.

__global__ __launch_bounds__(256) void attn_edge(
        const unsigned short* __restrict__ qb, const unsigned short* __restrict__ kvb,
        const int* __restrict__ base, const int* __restrict__ koff,
        unsigned short* __restrict__ attnb) {
    __shared__ float red[2][64][9];
    const int lane = threadIdx.x & 63;
    const int wave = threadIdx.x >> 6;
    const int rw = wave >> 1, part = wave & 1;
    const int s = blockIdx.x * 2 + rw;
    const int half = lane >> 5, hl = lane & 31;

    const uint4 qq = *((const uint4*)(qb + (size_t)(s * 2 + half) * C_) + hl);
    const float q0 = bflo(qq.x), q1 = bfhi(qq.x), q2 = bflo(qq.y), q3 = bfhi(qq.y);
    const float q4 = bflo(qq.z), q5 = bfhi(qq.z), q6 = bflo(qq.w), q7 = bfhi(qq.w);

    float a0 = 0.f, a1 = 0.f, a2 = 0.f, a3 = 0.f, a4 = 0.f, a5 = 0.f, a6 = 0.f, a7 = 0.f;
    float wsum = 0.f;
    const float scale = 0.17677669529663687f;   // 1/sqrt(32)

    auto edge = [&](const uint4& kk, const uint4& vv) {
        float p = q0 * bflo(kk.x) + q1 * bfhi(kk.x)
                + q2 * bflo(kk.y) + q3 * bfhi(kk.y)
                + q4 * bflo(kk.z) + q5 * bfhi(kk.z)
                + q6 * bflo(kk.w) + q7 * bfhi(kk.w);
        p += __shfl_xor(p, 1);
        p += __shfl_xor(p, 2);
        const float w = __expf(p * scale);
        a0 = fmaf(w, bflo(vv.x), a0); a1 = fmaf(w, bfhi(vv.x), a1);
        a2 = fmaf(w, bflo(vv.y), a2); a3 = fmaf(w, bfhi(vv.y), a3);
        a4 = fmaf(w, bflo(vv.z), a4); a5 = fmaf(w, bfhi(vv.z), a5);
        a6 = fmaf(w, bflo(vv.w), a6); a7 = fmaf(w, bfhi(vv.w), a7);
        wsum += w;
    };
    auto fetch = [&](int my, int t, uint4& kk, uint4& vv) {
        int o = __builtin_amdgcn_readlane(my, part + 2 * t);
        const uint4* p = (const uint4*)(kvb + o + half * 512);
        kk = p[hl]; vv = p[32 + hl];
    };

    // two k-buckets: [base[s],base[s+1]) then [base[S+s],base[S+s+1]) — each has a
    // 4 MB kvb working set that fits one XCD L2.
#pragma unroll
    for (int seg = 0; seg < 2; ++seg) {
        const int cb = seg * S_ + s;
        const int e0 = __builtin_amdgcn_readfirstlane(base[cb]);
        const int e1 = __builtin_amdgcn_readfirstlane(base[cb + 1]);
        for (int b0 = e0; b0 < e1; b0 += 64) {
            const int m = min(64, e1 - b0);
            const int my = koff[b0 + ((lane < m) ? lane : 0)];
            const int nm = (m > part) ? ((m - part + 1) >> 1) : 0;
            uint4 k0 = {}, v0 = {}, k1 = {}, v1 = {};
            uint4 k2 = {}, v2 = {}, k3 = {}, v3 = {};
            if (nm > 0) fetch(my, 0, k0, v0);
            if (nm > 1) fetch(my, 1, k1, v1);
            if (nm > 2) fetch(my, 2, k2, v2);
            if (nm > 3) fetch(my, 3, k3, v3);
            int t = 0;
            for (; t + 7 < nm; t += 4) {
                edge(k0, v0); fetch(my, t + 4, k0, v0);
                edge(k1, v1); fetch(my, t + 5, k1, v1);
                edge(k2, v2); fetch(my, t + 6, k2, v2);
                edge(k3, v3); fetch(my, t + 7, k3, v3);
            }
            const int rem = nm - t;   // 0..7
            if (rem > 0) { edge(k0, v0); if (rem > 4) fetch(my, t + 4, k0, v0); }
            if (rem > 1) { edge(k1, v1); if (rem > 5) fetch(my, t + 5, k1, v1); }
            if (rem > 2) { edge(k2, v2); if (rem > 6) fetch(my, t + 6, k2, v2); }
            if (rem > 3) edge(k3, v3);
            if (rem > 4) edge(k0, v0);
            if (rem > 5) edge(k1, v1);
            if (rem > 6) edge(k2, v2);
        }
    }

    if (part == 1) {
        float* r = red[rw][lane];
        r[0] = a0; r[1] = a1; r[2] = a2; r[3] = a3;
        r[4] = a4; r[5] = a5; r[6] = a6; r[7] = a7; r[8] = wsum;
    }
    __syncthreads();
    if (part == 0) {
        const float* r = red[rw][lane];
        a0 += r[0]; a1 += r[1]; a2 += r[2]; a3 += r[3];
        a4 += r[4]; a5 += r[5]; a6 += r[6]; a7 += r[7]; wsum += r[8];
        const float inv = 1.0f / wsum;
        uint4 o;
        o.x = (unsigned)f2bf(a0 * inv) | ((unsigned)f2bf(a1 * inv) << 16);
        o.y = (unsigned)f2bf(a2 * inv) | ((unsigned)f2bf(a3 * inv) << 16);
        o.z = (unsigned)f2bf(a4 * inv) | ((unsigned)f2bf(a5 * inv) << 16);
        o.w = (unsigned)f2bf(a6 * inv) | ((unsigned)f2bf(a7 * inv) << 16);
        *((uint4*)(attnb + (size_t)(s * 2 + half) * C_) + hl) = o;
    }
}

// ---------------- Kernel C: output projection (weights-in-registers) ----------------

__global__ __launch_bounds__(256) void gemm_proj(
        const unsigned short* __restrict__ attnb, const unsigned short* __restrict__ Wxb,
        const float* __restrict__ bx, float* __restrict__ out) {
    __shared__ __align__(16) unsigned short As[64][264];
    const int tid = threadIdx.x;
    const int nb = blockIdx.x & 3, mg = blockIdx.x >> 2;
    const int lane = tid & 63, wave = tid >> 6;
    const int l16 = lane & 15, quad = lane >> 4;
    const int colz = (nb << 6) + (wave << 4);

    const unsigned short* Wrow = Wxb + (size_t)(colz + l16) * C_;
    bf16x8_t breg[8];
#pragma unroll
    for (int ks = 0; ks < 8; ++ks)
        breg[ks] = *(const bf16x8_t*)(Wrow + ks * 32 + quad * 8);
    const float bcol = bx[colz + l16];

    const int mbase = mg * 64;
#pragma unroll
    for (int it = 0; it < 8; ++it) {
        int l = it * 256 + tid;
        int r = l >> 5, cc = (l & 31) << 3;
        *(uint4*)&As[r][cc] = *(const uint4*)&attnb[(size_t)(mbase + r) * C_ + cc];
    }
    __syncthreads();
#pragma unroll
    for (int mt = 0; mt < 4; ++mt) {
        f32x4_t acc = {0.f, 0.f, 0.f, 0.f};
#pragma unroll
        for (int ks = 0; ks < 8; ++ks) {
            bf16x8_t a = *(const bf16x8_t*)&As[mt * 16 + l16][ks * 32 + quad * 8];
            acc = __builtin_amdgcn_mfma_f32_16x16x32_bf16(a, breg[ks], acc, 0, 0, 0);
        }
        const int row0 = mbase + mt * 16 + quad * 4;
#pragma unroll
        for (int r = 0; r < 4; ++r)
            out[(size_t)(row0 + r) * C_ + colz + l16] = acc[r] + bcol;
    }
}

// ---------------- launch ----------------

extern "C" void kernel_launch(void* const* d_in, const int* in_sizes, int n_in,
                              void* d_out, int out_size, void* d_ws, size_t ws_size,
                              hipStream_t stream) {
    const float* x  = (const float*)d_in[0];
    const int* q_id = (const int*)d_in[1];
    const int* k_id = (const int*)d_in[2];
    const float* Wq = (const float*)d_in[3];
    const float* bq = (const float*)d_in[4];
    const float* Wk = (const float*)d_in[5];
    const float* bk = (const float*)d_in[6];
    const float* Wv = (const float*)d_in[7];
    const float* bv = (const float*)d_in[8];
    const float* Wx = (const float*)d_in[9];
    const float* bx = (const float*)d_in[10];
    float* out = (float*)d_out;

    char* ws = (char*)d_ws;
    unsigned short* xb    = (unsigned short*)ws;   ws += (size_t)MR * C_ * 2;
    unsigned short* qb    = (unsigned short*)ws;   ws += (size_t)MR * C_ * 2;
    unsigned short* kvb   = (unsigned short*)ws;   ws += (size_t)MR * 512 * 2;
    unsigned short* attnb = (unsigned short*)ws;   ws += (size_t)MR * C_ * 2;
    unsigned short* Wb    = (unsigned short*)ws;   ws += (size_t)4 * C_ * C_ * 2;
    int* count = (int*)ws;                         ws += 2 * S_ * 4;
    int* bst   = (int*)ws;                         ws += BST_INTS * 4;
    int* base  = (int*)ws;                         ws += (2 * S_ + 1) * 4;
    int* cursor = (int*)ws;                        ws += 2 * S_ * 4;
    int* koff_sorted = (int*)ws;

    hipMemsetAsync(count, 0, (2 * S_ + BST_INTS) * sizeof(int), stream);   // count + barrier state
    fusedA<<<NB, 256, 0, stream>>>(x, q_id, k_id, Wq, bq, Wk, bk, Wv, bv, Wx,
                                   xb, qb, kvb, Wb, count, bst, base, cursor, koff_sorted);
    attn_edge<<<S_ / 2, 256, 0, stream>>>(qb, kvb, base, koff_sorted, attnb);
    gemm_proj<<<512, 256, 0, stream>>>(attnb, Wb + (size_t)3 * C_ * C_, bx, out);
}

// Round 5
// 144.002 us; speedup vs baseline: 2.5108x; 1.1275x over previous
//
#include <hip/hip_runtime.h>

// Problem constants (fixed by the dataset)
constexpr int S_  = 4096;
constexpr int B_  = 2;
constexpr int C_  = 256;
constexpr int H_  = 8;
constexpr int E_  = 131072;
constexpr int MR  = S_ * B_;   // 8192 rows for all GEMMs
constexpr int PREP_BLOCKS = 640;   // 512 hist + 128 W-cast

typedef __attribute__((ext_vector_type(8))) short bf16x8_t;
typedef __attribute__((ext_vector_type(4))) float f32x4_t;

__device__ __forceinline__ unsigned short f2bf(float f) {
    unsigned int u = __float_as_uint(f);
    u += 0x7fffu + ((u >> 16) & 1u);   // round-to-nearest-even
    return (unsigned short)(u >> 16);
}
__device__ __forceinline__ float bflo(unsigned int u) { return __uint_as_float(u << 16); }
__device__ __forceinline__ float bfhi(unsigned int u) { return __uint_as_float(u & 0xffff0000u); }

__device__ __forceinline__ void cast8(const float* __restrict__ src, unsigned short* __restrict__ dst, int i) {
    const float4* s = (const float4*)src + (size_t)i * 2;
    float4 a = s[0], b = s[1];
    uint4 o;
    o.x = (unsigned)f2bf(a.x) | ((unsigned)f2bf(a.y) << 16);
    o.y = (unsigned)f2bf(a.z) | ((unsigned)f2bf(a.w) << 16);
    o.z = (unsigned)f2bf(b.x) | ((unsigned)f2bf(b.y) << 16);
    o.w = (unsigned)f2bf(b.z) | ((unsigned)f2bf(b.w) << 16);
    *((uint4*)dst + i) = o;
}

// ---------------- K1: bucketed histogram + W casts; last block does the scan ----------------
// count/base/cursor have 2S entries: bucket A (k<2048) in [0,S), bucket B in [S,2S).

__global__ __launch_bounds__(256) void prep_kernel(
        const int* __restrict__ q_id, const int* __restrict__ k_id,
        const float* __restrict__ Wq, const float* __restrict__ Wk,
        const float* __restrict__ Wv, const float* __restrict__ Wx,
        unsigned short* __restrict__ Wb,
        int* __restrict__ count, int* done,
        int* __restrict__ base, int* __restrict__ cursor) {
    const int bid = blockIdx.x, tid = threadIdx.x;
    if (bid < 512) {
        int e = bid * 256 + tid;
        int q = q_id[e], k = k_id[e];
        atomicAdd(&count[q + ((k >> 11) << 12)], 1);   // bucket = (k>=2048)
    } else {
        int idx = bid - 512;
        int z = idx >> 5;
        const float* src = (z == 0) ? Wq : (z == 1) ? Wk : (z == 2) ? Wv : Wx;
        cast8(src, Wb + (size_t)z * (C_ * C_), (idx & 31) * 256 + tid);
    }

    // ---- last-arriving block performs the 8192-entry exclusive scan ----
    __shared__ int amLast;
    __syncthreads();   // vmcnt(0): my atomics/stores are complete before the done-add
    if (tid == 0) {
        int d = __hip_atomic_fetch_add(done, 1, __ATOMIC_RELAXED, __HIP_MEMORY_SCOPE_AGENT);
        amLast = (d == PREP_BLOCKS - 1);
    }
    __syncthreads();
    if (!amLast) return;
    __builtin_amdgcn_fence(__ATOMIC_ACQUIRE, "agent");   // invalidate L1/L2 before reading count

    const int lane = tid & 63, w = tid >> 6;
    const int4* cp = (const int4*)count;
    int4 c[8];
#pragma unroll
    for (int j = 0; j < 8; ++j) c[j] = cp[tid * 8 + j];
    int tsum = 0;
#pragma unroll
    for (int j = 0; j < 8; ++j) tsum += c[j].x + c[j].y + c[j].z + c[j].w;
    int incl = tsum;
#pragma unroll
    for (int off = 1; off < 64; off <<= 1) {
        int y = __shfl_up(incl, off);
        if (lane >= off) incl += y;
    }
    __shared__ int wsums[4];
    if (lane == 63) wsums[w] = incl;
    __syncthreads();
    int ws0 = wsums[0], ws1 = wsums[1], ws2 = wsums[2];
    if (tid == 0) base[2 * S_] = E_;
    int woff = (w > 0 ? ws0 : 0) + (w > 1 ? ws1 : 0) + (w > 2 ? ws2 : 0);
    int run = woff + incl - tsum;
    int idx = tid * 32;
#define EMIT(V) { base[idx] = run; cursor[idx] = run; run += (V); ++idx; }
#pragma unroll
    for (int j = 0; j < 8; ++j) {
        EMIT(c[j].x) EMIT(c[j].y) EMIT(c[j].z) EMIT(c[j].w)
    }
#undef EMIT
}

// ---------------- K2: scatter + QKV GEMM (A cast fp32->bf16 during staging) ----------------
// blocks [0,512): gemm — 4 n-blocks x 128 m-groups (64 rows). Per wave: 3 B-strips
// (Wq,Wk,Wv) in 96 VGPRs; A staged once from fp32 x. blocks [512,1024): bucketed scatter.

__global__ __launch_bounds__(256) void scatter_qkv_kernel(
        const float* __restrict__ x,
        const int* __restrict__ q_id, const int* __restrict__ k_id,
        int* __restrict__ cursor, int* __restrict__ koff,
        const unsigned short* __restrict__ Wb,
        const float* __restrict__ bq, const float* __restrict__ bk, const float* __restrict__ bv,
        unsigned short* __restrict__ qb, unsigned short* __restrict__ kvb) {
    __shared__ __align__(16) unsigned short As[64][264];   // 33.8 KB, +8 pad
    const int bid = blockIdx.x, tid = threadIdx.x;
    if (bid >= 512) {
        int e = (bid - 512) * 256 + tid;
        int q = q_id[e], k = k_id[e];
        int pos = atomicAdd(&cursor[q + ((k >> 11) << 12)], 1);
        koff[pos] = k << 10;               // element offset of row-pair in kvb
        return;
    }
    const int nb = bid & 3, mg = bid >> 2;
    const int lane = tid & 63, wave = tid >> 6;
    const int l16 = lane & 15, quad = lane >> 4;
    const int colz = (nb << 6) + (wave << 4);

    // Three B-strips: rows [colz, colz+16) of Wq, Wk, Wv
    bf16x8_t breg[3][8];
#pragma unroll
    for (int z = 0; z < 3; ++z) {
        const unsigned short* Wrow = Wb + (size_t)z * (C_ * C_) + (size_t)(colz + l16) * C_;
#pragma unroll
        for (int ks = 0; ks < 8; ++ks)
            breg[z][ks] = *(const bf16x8_t*)(Wrow + ks * 32 + quad * 8);
    }
    const float bc0 = bq[colz + l16];
    const float bc1 = bk[colz + l16];
    const float bc2 = bv[colz + l16];

    const int mbase = mg * 64;
    // stage A: 64 rows x 256 cols, fp32 -> bf16 into LDS
#pragma unroll
    for (int it = 0; it < 8; ++it) {
        int u = it * 256 + tid;
        int r = u >> 5, cc = (u & 31) << 3;
        const float4* s = (const float4*)(x + (size_t)(mbase + r) * C_ + cc);
        float4 a = s[0], b = s[1];
        uint4 o;
        o.x = (unsigned)f2bf(a.x) | ((unsigned)f2bf(a.y) << 16);
        o.y = (unsigned)f2bf(a.z) | ((unsigned)f2bf(a.w) << 16);
        o.z = (unsigned)f2bf(b.x) | ((unsigned)f2bf(b.y) << 16);
        o.w = (unsigned)f2bf(b.z) | ((unsigned)f2bf(b.w) << 16);
        *(uint4*)&As[r][cc] = o;
    }
    __syncthreads();

#pragma unroll
    for (int mt = 0; mt < 4; ++mt) {
        bf16x8_t a[8];
#pragma unroll
        for (int ks = 0; ks < 8; ++ks)
            a[ks] = *(const bf16x8_t*)&As[mt * 16 + l16][ks * 32 + quad * 8];
        const int row0 = mbase + mt * 16 + quad * 4;
        {   // q
            f32x4_t acc = {0.f, 0.f, 0.f, 0.f};
#pragma unroll
            for (int ks = 0; ks < 8; ++ks)
                acc = __builtin_amdgcn_mfma_f32_16x16x32_bf16(a[ks], breg[0][ks], acc, 0, 0, 0);
#pragma unroll
            for (int r = 0; r < 4; ++r)
                qb[(size_t)(row0 + r) * 256 + colz + l16] = f2bf(acc[r] + bc0);
        }
        {   // k  (kvb cols [0,256))
            f32x4_t acc = {0.f, 0.f, 0.f, 0.f};
#pragma unroll
            for (int ks = 0; ks < 8; ++ks)
                acc = __builtin_amdgcn_mfma_f32_16x16x32_bf16(a[ks], breg[1][ks], acc, 0, 0, 0);
#pragma unroll
            for (int r = 0; r < 4; ++r)
                kvb[(size_t)(row0 + r) * 512 + colz + l16] = f2bf(acc[r] + bc1);
        }
        {   // v  (kvb cols [256,512))
            f32x4_t acc = {0.f, 0.f, 0.f, 0.f};
#pragma unroll
            for (int ks = 0; ks < 8; ++ks)
                acc = __builtin_amdgcn_mfma_f32_16x16x32_bf16(a[ks], breg[2][ks], acc, 0, 0, 0);
#pragma unroll
            for (int r = 0; r < 4; ++r)
                kvb[(size_t)(row0 + r) * 512 + 256 + colz + l16] = f2bf(acc[r] + bc2);
        }
    }
}

// ---------------- K3: edge attention, k-bucketed two-pass gather ----------------

__global__ __launch_bounds__(256) void attn_edge(
        const unsigned short* __restrict__ qb, const unsigned short* __restrict__ kvb,
        const int* __restrict__ base, const int* __restrict__ koff,
        unsigned short* __restrict__ attnb) {
    __shared__ float red[2][64][9];
    const int lane = threadIdx.x & 63;
    const int wave = threadIdx.x >> 6;
    const int rw = wave >> 1, part = wave & 1;
    const int s = blockIdx.x * 2 + rw;
    const int half = lane >> 5, hl = lane & 31;

    const uint4 qq = *((const uint4*)(qb + (size_t)(s * 2 + half) * C_) + hl);
    const float q0 = bflo(qq.x), q1 = bfhi(qq.x), q2 = bflo(qq.y), q3 = bfhi(qq.y);
    const float q4 = bflo(qq.z), q5 = bfhi(qq.z), q6 = bflo(qq.w), q7 = bfhi(qq.w);

    float a0 = 0.f, a1 = 0.f, a2 = 0.f, a3 = 0.f, a4 = 0.f, a5 = 0.f, a6 = 0.f, a7 = 0.f;
    float wsum = 0.f;
    const float scale = 0.17677669529663687f;   // 1/sqrt(32)

    auto edge = [&](const uint4& kk, const uint4& vv) {
        float p = q0 * bflo(kk.x) + q1 * bfhi(kk.x)
                + q2 * bflo(kk.y) + q3 * bfhi(kk.y)
                + q4 * bflo(kk.z) + q5 * bfhi(kk.z)
                + q6 * bflo(kk.w) + q7 * bfhi(kk.w);
        p += __shfl_xor(p, 1);
        p += __shfl_xor(p, 2);
        const float w = __expf(p * scale);
        a0 = fmaf(w, bflo(vv.x), a0); a1 = fmaf(w, bfhi(vv.x), a1);
        a2 = fmaf(w, bflo(vv.y), a2); a3 = fmaf(w, bfhi(vv.y), a3);
        a4 = fmaf(w, bflo(vv.z), a4); a5 = fmaf(w, bfhi(vv.z), a5);
        a6 = fmaf(w, bflo(vv.w), a6); a7 = fmaf(w, bfhi(vv.w), a7);
        wsum += w;
    };
    auto fetch = [&](int my, int t, uint4& kk, uint4& vv) {
        int o = __builtin_amdgcn_readlane(my, part + 2 * t);
        const uint4* p = (const uint4*)(kvb + o + half * 512);
        kk = p[hl]; vv = p[32 + hl];
    };

    // two k-buckets; each has a ~4 MB kvb working set that fits one XCD L2.
#pragma unroll
    for (int seg = 0; seg < 2; ++seg) {
        const int cb = seg * S_ + s;
        const int e0 = __builtin_amdgcn_readfirstlane(base[cb]);
        const int e1 = __builtin_amdgcn_readfirstlane(base[cb + 1]);
        for (int b0 = e0; b0 < e1; b0 += 64) {
            const int m = min(64, e1 - b0);
            const int my = koff[b0 + ((lane < m) ? lane : 0)];
            const int nm = (m > part) ? ((m - part + 1) >> 1) : 0;
            uint4 k0 = {}, v0 = {}, k1 = {}, v1 = {};
            uint4 k2 = {}, v2 = {}, k3 = {}, v3 = {};
            if (nm > 0) fetch(my, 0, k0, v0);
            if (nm > 1) fetch(my, 1, k1, v1);
            if (nm > 2) fetch(my, 2, k2, v2);
            if (nm > 3) fetch(my, 3, k3, v3);
            int t = 0;
            for (; t + 7 < nm; t += 4) {
                edge(k0, v0); fetch(my, t + 4, k0, v0);
                edge(k1, v1); fetch(my, t + 5, k1, v1);
                edge(k2, v2); fetch(my, t + 6, k2, v2);
                edge(k3, v3); fetch(my, t + 7, k3, v3);
            }
            const int rem = nm - t;   // 0..7
            if (rem > 0) { edge(k0, v0); if (rem > 4) fetch(my, t + 4, k0, v0); }
            if (rem > 1) { edge(k1, v1); if (rem > 5) fetch(my, t + 5, k1, v1); }
            if (rem > 2) { edge(k2, v2); if (rem > 6) fetch(my, t + 6, k2, v2); }
            if (rem > 3) edge(k3, v3);
            if (rem > 4) edge(k0, v0);
            if (rem > 5) edge(k1, v1);
            if (rem > 6) edge(k2, v2);
        }
    }

    if (part == 1) {
        float* r = red[rw][lane];
        r[0] = a0; r[1] = a1; r[2] = a2; r[3] = a3;
        r[4] = a4; r[5] = a5; r[6] = a6; r[7] = a7; r[8] = wsum;
    }
    __syncthreads();
    if (part == 0) {
        const float* r = red[rw][lane];
        a0 += r[0]; a1 += r[1]; a2 += r[2]; a3 += r[3];
        a4 += r[4]; a5 += r[5]; a6 += r[6]; a7 += r[7]; wsum += r[8];
        const float inv = 1.0f / wsum;
        uint4 o;
        o.x = (unsigned)f2bf(a0 * inv) | ((unsigned)f2bf(a1 * inv) << 16);
        o.y = (unsigned)f2bf(a2 * inv) | ((unsigned)f2bf(a3 * inv) << 16);
        o.z = (unsigned)f2bf(a4 * inv) | ((unsigned)f2bf(a5 * inv) << 16);
        o.w = (unsigned)f2bf(a6 * inv) | ((unsigned)f2bf(a7 * inv) << 16);
        *((uint4*)(attnb + (size_t)(s * 2 + half) * C_) + hl) = o;
    }
}

// ---------------- K4: output projection (weights-in-registers) ----------------

__global__ __launch_bounds__(256) void gemm_proj(
        const unsigned short* __restrict__ attnb, const unsigned short* __restrict__ Wxb,
        const float* __restrict__ bx, float* __restrict__ out) {
    __shared__ __align__(16) unsigned short As[64][264];
    const int tid = threadIdx.x;
    const int nb = blockIdx.x & 3, mg = blockIdx.x >> 2;
    const int lane = tid & 63, wave = tid >> 6;
    const int l16 = lane & 15, quad = lane >> 4;
    const int colz = (nb << 6) + (wave << 4);

    const unsigned short* Wrow = Wxb + (size_t)(colz + l16) * C_;
    bf16x8_t breg[8];
#pragma unroll
    for (int ks = 0; ks < 8; ++ks)
        breg[ks] = *(const bf16x8_t*)(Wrow + ks * 32 + quad * 8);
    const float bcol = bx[colz + l16];

    const int mbase = mg * 64;
#pragma unroll
    for (int it = 0; it < 8; ++it) {
        int l = it * 256 + tid;
        int r = l >> 5, cc = (l & 31) << 3;
        *(uint4*)&As[r][cc] = *(const uint4*)&attnb[(size_t)(mbase + r) * C_ + cc];
    }
    __syncthreads();
#pragma unroll
    for (int mt = 0; mt < 4; ++mt) {
        f32x4_t acc = {0.f, 0.f, 0.f, 0.f};
#pragma unroll
        for (int ks = 0; ks < 8; ++ks) {
            bf16x8_t a = *(const bf16x8_t*)&As[mt * 16 + l16][ks * 32 + quad * 8];
            acc = __builtin_amdgcn_mfma_f32_16x16x32_bf16(a, breg[ks], acc, 0, 0, 0);
        }
        const int row0 = mbase + mt * 16 + quad * 4;
#pragma unroll
        for (int r = 0; r < 4; ++r)
            out[(size_t)(row0 + r) * C_ + colz + l16] = acc[r] + bcol;
    }
}

// ---------------- launch ----------------

extern "C" void kernel_launch(void* const* d_in, const int* in_sizes, int n_in,
                              void* d_out, int out_size, void* d_ws, size_t ws_size,
                              hipStream_t stream) {
    const float* x  = (const float*)d_in[0];
    const int* q_id = (const int*)d_in[1];
    const int* k_id = (const int*)d_in[2];
    const float* Wq = (const float*)d_in[3];
    const float* bq = (const float*)d_in[4];
    const float* Wk = (const float*)d_in[5];
    const float* bk = (const float*)d_in[6];
    const float* Wv = (const float*)d_in[7];
    const float* bv = (const float*)d_in[8];
    const float* Wx = (const float*)d_in[9];
    const float* bx = (const float*)d_in[10];
    float* out = (float*)d_out;

    char* ws = (char*)d_ws;
    unsigned short* qb    = (unsigned short*)ws;   ws += (size_t)MR * C_ * 2;
    unsigned short* kvb   = (unsigned short*)ws;   ws += (size_t)MR * 512 * 2;
    unsigned short* attnb = (unsigned short*)ws;   ws += (size_t)MR * C_ * 2;
    unsigned short* Wb    = (unsigned short*)ws;   ws += (size_t)4 * C_ * C_ * 2;
    int* count = (int*)ws;                         ws += 2 * S_ * 4;
    int* done  = (int*)ws;                         ws += 16 * 4;
    int* base  = (int*)ws;                         ws += (2 * S_ + 1) * 4;
    int* cursor = (int*)ws;                        ws += 2 * S_ * 4;
    int* koff_sorted = (int*)ws;

    hipMemsetAsync(count, 0, (2 * S_ + 16) * sizeof(int), stream);   // count + done
    prep_kernel<<<PREP_BLOCKS, 256, 0, stream>>>(q_id, k_id, Wq, Wk, Wv, Wx, Wb,
                                                 count, done, base, cursor);
    scatter_qkv_kernel<<<1024, 256, 0, stream>>>(x, q_id, k_id, cursor, koff_sorted,
                                                 Wb, bq, bk, bv, qb, kvb);
    attn_edge<<<S_ / 2, 256, 0, stream>>>(qb, kvb, base, koff_sorted, attnb);
    gemm_proj<<<512, 256, 0, stream>>>(attnb, Wb + (size_t)3 * C_ * C_, bx, out);
}